// Round 1
// baseline (267.206 us; speedup 1.0000x reference)
//
#include <hip/hip_runtime.h>
#include <cstdint>

#define NCH 128   // IN_CH == OUT_CH == 128
#define BM  64    // node-GEMM rows per block

// ---------------------------------------------------------------------------
// prep: a = softmax(attn_weights); Wp[o][d] = W[o][d] * a[d]
// single block, 128 threads
// ---------------------------------------------------------------------------
__global__ __launch_bounds__(128)
void prep_kernel(const float* __restrict__ aw,
                 const float* __restrict__ W,
                 float* __restrict__ Wp) {
    __shared__ float sw[NCH];
    const int t = threadIdx.x;
    sw[t] = aw[t];
    __syncthreads();
    float m = -1e30f;
#pragma unroll
    for (int d = 0; d < NCH; ++d) m = fmaxf(m, sw[d]);
    float s = 0.f;
#pragma unroll
    for (int d = 0; d < NCH; ++d) s += expf(sw[d] - m);
    const float av = expf(sw[t] - m) / s;
    __syncthreads();
    sw[t] = av;          // sw now holds a[d]
    __syncthreads();
    // Wp[o][t] = W[o][t] * a[t], coalesced over t
    for (int o = 0; o < NCH; ++o)
        Wp[o * NCH + t] = W[o * NCH + t] * sw[t];
}

// ---------------------------------------------------------------------------
// node GEMM: Y[n][o] = sum_d X[n][d] * Wp[o][d]   (fp32, LDS-tiled)
// block = 256 threads, BM=64 rows per block, full 128 cols
// thread (tr = t&15, tc = t>>4) computes rows tr*4..+3  x  cols tc*8..+7
// ---------------------------------------------------------------------------
__global__ __launch_bounds__(256)
void node_gemm_kernel(const float* __restrict__ X,
                      const float* __restrict__ Wp,
                      float* __restrict__ Y, int M) {
    __shared__ float sW[NCH][NCH + 1];   // +1 pad: conflict-free broadcast reads
    __shared__ float sX[BM][NCH + 1];
    const int t = threadIdx.x;
    const int row0 = blockIdx.x * BM;

    // stage Wp (128x128) via float4
    for (int i = t; i < NCH * (NCH / 4); i += 256) {
        const int o = i >> 5, q = i & 31;
        const float4 v = reinterpret_cast<const float4*>(Wp)[o * 32 + q];
        sW[o][q * 4 + 0] = v.x; sW[o][q * 4 + 1] = v.y;
        sW[o][q * 4 + 2] = v.z; sW[o][q * 4 + 3] = v.w;
    }
    // stage X tile (64x128) via float4
    for (int i = t; i < BM * (NCH / 4); i += 256) {
        const int r = i >> 5, q = i & 31;
        const int gr = row0 + r;
        float4 v = make_float4(0.f, 0.f, 0.f, 0.f);
        if (gr < M) v = reinterpret_cast<const float4*>(X)[(size_t)gr * 32 + q];
        sX[r][q * 4 + 0] = v.x; sX[r][q * 4 + 1] = v.y;
        sX[r][q * 4 + 2] = v.z; sX[r][q * 4 + 3] = v.w;
    }
    __syncthreads();

    const int tr = t & 15;
    const int tc = t >> 4;
    float acc[4][8];
#pragma unroll
    for (int i = 0; i < 4; ++i)
#pragma unroll
        for (int j = 0; j < 8; ++j) acc[i][j] = 0.f;

#pragma unroll 4
    for (int d = 0; d < NCH; ++d) {
        float xr[4], wc[8];
#pragma unroll
        for (int i = 0; i < 4; ++i) xr[i] = sX[tr * 4 + i][d];
#pragma unroll
        for (int j = 0; j < 8; ++j) wc[j] = sW[tc * 8 + j][d];
#pragma unroll
        for (int i = 0; i < 4; ++i)
#pragma unroll
            for (int j = 0; j < 8; ++j) acc[i][j] += xr[i] * wc[j];
    }

#pragma unroll
    for (int i = 0; i < 4; ++i) {
        const int gr = row0 + tr * 4 + i;
        if (gr < M) {
            float* dst = Y + (size_t)gr * NCH + tc * 8;
            float4 v0 = make_float4(acc[i][0], acc[i][1], acc[i][2], acc[i][3]);
            float4 v1 = make_float4(acc[i][4], acc[i][5], acc[i][6], acc[i][7]);
            reinterpret_cast<float4*>(dst)[0] = v0;
            reinterpret_cast<float4*>(dst)[1] = v1;
        }
    }
}

// ---------------------------------------------------------------------------
// edge kernel: out[e][:] = relu(Y[src[e]][:] + Y[tgt[e]][:] + b[:])
// 32 threads per edge (float4 each), 8 edges per 256-thread block
// ---------------------------------------------------------------------------
__global__ __launch_bounds__(256)
void edge_out_kernel(const float* __restrict__ Y,
                     const int* __restrict__ ei,
                     const float* __restrict__ bias,
                     float* __restrict__ out, int E) {
    const int t = threadIdx.x;
    const int e = blockIdx.x * 8 + (t >> 5);
    const int q = t & 31;
    if (e >= E) return;
    const int s = ei[e];
    const int g = ei[E + e];
    const float4 vs = reinterpret_cast<const float4*>(Y)[(size_t)s * 32 + q];
    const float4 vt = reinterpret_cast<const float4*>(Y)[(size_t)g * 32 + q];
    const float4 vb = reinterpret_cast<const float4*>(bias)[q];
    float4 r;
    r.x = fmaxf(vs.x + vt.x + vb.x, 0.f);
    r.y = fmaxf(vs.y + vt.y + vb.y, 0.f);
    r.z = fmaxf(vs.z + vt.z + vb.z, 0.f);
    r.w = fmaxf(vs.w + vt.w + vb.w, 0.f);
    reinterpret_cast<float4*>(out)[(size_t)e * 32 + q] = r;
}

// ---------------------------------------------------------------------------
// fallback (only if ws too small for Y): fully self-contained direct edge GEMM
// ---------------------------------------------------------------------------
__global__ __launch_bounds__(256)
void direct_edge_kernel(const float* __restrict__ X,
                        const int* __restrict__ ei,
                        const float* __restrict__ aw,
                        const float* __restrict__ W,
                        const float* __restrict__ bias,
                        float* __restrict__ out, int E) {
    __shared__ float sW[NCH][NCH + 1];
    __shared__ float sa[NCH];
    __shared__ float sE[8][NCH + 4];
    const int t = threadIdx.x;
    if (t < NCH) sa[t] = aw[t];
    __syncthreads();
    float m = -1e30f;
#pragma unroll
    for (int d = 0; d < NCH; ++d) m = fmaxf(m, sa[d]);
    float ssum = 0.f;
#pragma unroll
    for (int d = 0; d < NCH; ++d) ssum += expf(sa[d] - m);
    const float av = (t < NCH) ? expf(sa[t] - m) / ssum : 0.f;
    __syncthreads();
    if (t < NCH) sa[t] = av;
    __syncthreads();
    for (int i = t; i < NCH * 32; i += 256) {
        const int o = i >> 5, q = i & 31;
        float4 v = reinterpret_cast<const float4*>(W)[o * 32 + q];
        sW[o][q * 4 + 0] = v.x * sa[q * 4 + 0];
        sW[o][q * 4 + 1] = v.y * sa[q * 4 + 1];
        sW[o][q * 4 + 2] = v.z * sa[q * 4 + 2];
        sW[o][q * 4 + 3] = v.w * sa[q * 4 + 3];
    }
    __syncthreads();
    const int le = t >> 5, q = t & 31;
    for (int e0 = blockIdx.x * 8; e0 < E; e0 += gridDim.x * 8) {
        const int e = e0 + le;
        if (e < E) {
            const int s = ei[e];
            const int g = ei[E + e];
            const float4 vs = reinterpret_cast<const float4*>(X)[(size_t)s * 32 + q];
            const float4 vt = reinterpret_cast<const float4*>(X)[(size_t)g * 32 + q];
            sE[le][q * 4 + 0] = vs.x + vt.x;
            sE[le][q * 4 + 1] = vs.y + vt.y;
            sE[le][q * 4 + 2] = vs.z + vt.z;
            sE[le][q * 4 + 3] = vs.w + vt.w;
        }
        __syncthreads();
        if (e < E) {
            float a0 = 0.f, a1 = 0.f, a2 = 0.f, a3 = 0.f;
            const int o = q * 4;
#pragma unroll 4
            for (int d = 0; d < NCH; ++d) {
                const float x = sE[le][d];
                a0 += x * sW[o + 0][d];
                a1 += x * sW[o + 1][d];
                a2 += x * sW[o + 2][d];
                a3 += x * sW[o + 3][d];
            }
            float4 r;
            r.x = fmaxf(a0 + bias[o + 0], 0.f);
            r.y = fmaxf(a1 + bias[o + 1], 0.f);
            r.z = fmaxf(a2 + bias[o + 2], 0.f);
            r.w = fmaxf(a3 + bias[o + 3], 0.f);
            reinterpret_cast<float4*>(out)[(size_t)e * 32 + q] = r;
        }
        __syncthreads();
    }
}

// ---------------------------------------------------------------------------
extern "C" void kernel_launch(void* const* d_in, const int* in_sizes, int n_in,
                              void* d_out, int out_size, void* d_ws, size_t ws_size,
                              hipStream_t stream) {
    const float* X    = (const float*)d_in[0];   // [100000,128] f32
    const int*   ei   = (const int*)d_in[1];     // [2,625000] int32
    const float* aw   = (const float*)d_in[2];   // [128] f32
    const float* W    = (const float*)d_in[3];   // [128,128] f32
    const float* bias = (const float*)d_in[4];   // [128] f32
    float* out = (float*)d_out;

    const int M = in_sizes[0] / NCH;             // 100000 nodes
    const int E = in_sizes[1] / 2;               // 625000 edges

    const size_t wp_bytes = (size_t)NCH * NCH * sizeof(float);   // 64 KB
    const size_t y_off    = 65536;                                // aligned
    const size_t y_bytes  = (size_t)M * NCH * sizeof(float);      // 51.2 MB

    if (ws_size >= y_off + y_bytes && wp_bytes <= y_off) {
        float* Wp = (float*)d_ws;
        float* Y  = (float*)((char*)d_ws + y_off);
        prep_kernel<<<1, 128, 0, stream>>>(aw, W, Wp);
        node_gemm_kernel<<<(M + BM - 1) / BM, 256, 0, stream>>>(X, Wp, Y, M);
        edge_out_kernel<<<(E + 7) / 8, 256, 0, stream>>>(Y, ei, bias, out, E);
    } else {
        // self-contained fallback: direct per-edge GEMM
        int grid = (E + 7) / 8;
        if (grid > 32768) grid = 32768;
        direct_edge_kernel<<<grid, 256, 0, stream>>>(X, ei, aw, W, bias, out, E);
    }
}

// Round 2
// 155.550 us; speedup vs baseline: 1.7178x; 1.7178x over previous
//
#include <hip/hip_runtime.h>
#include <hip/hip_fp16.h>
#include <cstdint>

#define NCH 128   // IN_CH == OUT_CH == 128

typedef short short8v __attribute__((ext_vector_type(8)));
typedef float f32x4  __attribute__((ext_vector_type(4)));

// f32 -> bf16 bits, round-to-nearest-even (inputs are normal floats)
static __device__ __forceinline__ short f2bf(float f) {
    unsigned u = __float_as_uint(f);
    u += 0x7FFFu + ((u >> 16) & 1u);
    return (short)(u >> 16);
}
static __device__ __forceinline__ unsigned short f2h(float f) {
    return __half_as_ushort(__float2half(f));
}
static __device__ __forceinline__ float h2f(unsigned short u) {
    return __half2float(__ushort_as_half(u));
}

// ---------------------------------------------------------------------------
// prep: a = softmax(attn_weights); Wpb[o][d] = bf16(W[o][d] * a[d])
// ---------------------------------------------------------------------------
__global__ __launch_bounds__(128)
void prep_kernel(const float* __restrict__ aw,
                 const float* __restrict__ W,
                 short* __restrict__ Wpb) {
    __shared__ float sa[NCH];
    const int t = threadIdx.x;
    sa[t] = aw[t];
    __syncthreads();
    float m = -1e30f;
#pragma unroll
    for (int d = 0; d < NCH; ++d) m = fmaxf(m, sa[d]);
    float s = 0.f;
#pragma unroll
    for (int d = 0; d < NCH; ++d) s += expf(sa[d] - m);
    const float av = expf(sa[t] - m) / s;
    __syncthreads();
    sa[t] = av;
    __syncthreads();
    for (int o = 0; o < NCH; ++o)
        Wpb[o * NCH + t] = f2bf(W[o * NCH + t] * sa[t]);
}

// ---------------------------------------------------------------------------
// node GEMM via MFMA 16x16x32 bf16, no LDS:
//   Yh[n][o] = fp16( sum_d X[n][d] * Wp[o][d] )
// block = 256 (4 waves); block covers 64 rows; wave w covers rows w*16..+15,
// all 128 output cols (8 tiles of 16).
// A-frag: lane l needs X[row0 + (l&15)][ks*32 + (l>>4)*8 .. +7]  (8 contiguous)
// B-frag: lane l needs Wp[tile*16 + (l&15)][ks*32 + (l>>4)*8 .. +7]
// C/D:    col = lane&15 (in tile), row = (lane>>4)*4 + j   [m89-verified]
// ---------------------------------------------------------------------------
__global__ __launch_bounds__(256)
void node_gemm_mfma(const float* __restrict__ X,
                    const short* __restrict__ Wpb,
                    unsigned short* __restrict__ Yh, int M) {
    const int t    = threadIdx.x;
    const int wave = t >> 6;
    const int lane = t & 63;
    const int r    = lane & 15;
    const int kb   = lane >> 4;

    const int row  = blockIdx.x * 64 + wave * 16 + r;
    const int rowc = row < M ? row : M - 1;          // clamp; stores are guarded
    const float* xr = X + (size_t)rowc * NCH;

    short8v a[4];
#pragma unroll
    for (int ks = 0; ks < 4; ++ks) {
        const float4 f0 = *reinterpret_cast<const float4*>(xr + ks * 32 + kb * 8);
        const float4 f1 = *reinterpret_cast<const float4*>(xr + ks * 32 + kb * 8 + 4);
        short8v v;
        v[0] = f2bf(f0.x); v[1] = f2bf(f0.y); v[2] = f2bf(f0.z); v[3] = f2bf(f0.w);
        v[4] = f2bf(f1.x); v[5] = f2bf(f1.y); v[6] = f2bf(f1.z); v[7] = f2bf(f1.w);
        a[ks] = v;
    }

    const int orow0 = blockIdx.x * 64 + wave * 16 + kb * 4;
#pragma unroll
    for (int tile = 0; tile < 8; ++tile) {
        f32x4 acc = {0.f, 0.f, 0.f, 0.f};
        const short* wr = Wpb + (size_t)(tile * 16 + r) * NCH;
#pragma unroll
        for (int ks = 0; ks < 4; ++ks) {
            const short8v b = *reinterpret_cast<const short8v*>(wr + ks * 32 + kb * 8);
            acc = __builtin_amdgcn_mfma_f32_16x16x32_bf16(a[ks], b, acc, 0, 0, 0);
        }
        const int col = tile * 16 + r;
#pragma unroll
        for (int j = 0; j < 4; ++j) {
            const int orow = orow0 + j;
            if (orow < M) Yh[(size_t)orow * NCH + col] = f2h(acc[j]);
        }
    }
}

// ---------------------------------------------------------------------------
// edge kernel: out[e][:] = relu(Yh[src[e]][:] + Yh[tgt[e]][:] + b[:])
// 16 lanes per edge, each lane one 16B half8 chunk (8 channels); 16 edges/block
// ---------------------------------------------------------------------------
__global__ __launch_bounds__(256)
void edge_out_half(const unsigned short* __restrict__ Yh,
                   const int* __restrict__ ei,
                   const float* __restrict__ bias,
                   float* __restrict__ out, int E) {
    const int t = threadIdx.x;
    const int e = blockIdx.x * 16 + (t >> 4);
    const int q = t & 15;
    if (e >= E) return;
    const int s = ei[e];
    const int g = ei[E + e];

    const short8v hs = *reinterpret_cast<const short8v*>(Yh + (size_t)s * NCH + q * 8);
    const short8v ht = *reinterpret_cast<const short8v*>(Yh + (size_t)g * NCH + q * 8);
    const float4 b0 = *reinterpret_cast<const float4*>(bias + q * 8);
    const float4 b1 = *reinterpret_cast<const float4*>(bias + q * 8 + 4);

    float r[8];
#pragma unroll
    for (int j = 0; j < 8; ++j)
        r[j] = h2f((unsigned short)hs[j]) + h2f((unsigned short)ht[j]);
    r[0] += b0.x; r[1] += b0.y; r[2] += b0.z; r[3] += b0.w;
    r[4] += b1.x; r[5] += b1.y; r[6] += b1.z; r[7] += b1.w;
#pragma unroll
    for (int j = 0; j < 8; ++j) r[j] = fmaxf(r[j], 0.f);

    float* dst = out + (size_t)e * NCH + q * 8;
    reinterpret_cast<float4*>(dst)[0] = make_float4(r[0], r[1], r[2], r[3]);
    reinterpret_cast<float4*>(dst)[1] = make_float4(r[4], r[5], r[6], r[7]);
}

// ---------------------------------------------------------------------------
// fallback (only if ws too small): fully self-contained direct fp32 edge GEMM
// ---------------------------------------------------------------------------
__global__ __launch_bounds__(256)
void direct_edge_kernel(const float* __restrict__ X,
                        const int* __restrict__ ei,
                        const float* __restrict__ aw,
                        const float* __restrict__ W,
                        const float* __restrict__ bias,
                        float* __restrict__ out, int E) {
    __shared__ float sW[NCH][NCH + 1];
    __shared__ float sa[NCH];
    __shared__ float sE[8][NCH + 4];
    const int t = threadIdx.x;
    if (t < NCH) sa[t] = aw[t];
    __syncthreads();
    float m = -1e30f;
#pragma unroll
    for (int d = 0; d < NCH; ++d) m = fmaxf(m, sa[d]);
    float ssum = 0.f;
#pragma unroll
    for (int d = 0; d < NCH; ++d) ssum += expf(sa[d] - m);
    const float av = (t < NCH) ? expf(sa[t] - m) / ssum : 0.f;
    __syncthreads();
    if (t < NCH) sa[t] = av;
    __syncthreads();
    for (int i = t; i < NCH * 32; i += 256) {
        const int o = i >> 5, q = i & 31;
        float4 v = reinterpret_cast<const float4*>(W)[o * 32 + q];
        sW[o][q * 4 + 0] = v.x * sa[q * 4 + 0];
        sW[o][q * 4 + 1] = v.y * sa[q * 4 + 1];
        sW[o][q * 4 + 2] = v.z * sa[q * 4 + 2];
        sW[o][q * 4 + 3] = v.w * sa[q * 4 + 3];
    }
    __syncthreads();
    const int le = t >> 5, q = t & 31;
    for (int e0 = blockIdx.x * 8; e0 < E; e0 += gridDim.x * 8) {
        const int e = e0 + le;
        if (e < E) {
            const int s = ei[e];
            const int g = ei[E + e];
            const float4 vs = reinterpret_cast<const float4*>(X)[(size_t)s * 32 + q];
            const float4 vt = reinterpret_cast<const float4*>(X)[(size_t)g * 32 + q];
            sE[le][q * 4 + 0] = vs.x + vt.x;
            sE[le][q * 4 + 1] = vs.y + vt.y;
            sE[le][q * 4 + 2] = vs.z + vt.z;
            sE[le][q * 4 + 3] = vs.w + vt.w;
        }
        __syncthreads();
        if (e < E) {
            float a0 = 0.f, a1 = 0.f, a2 = 0.f, a3 = 0.f;
            const int o = q * 4;
#pragma unroll 4
            for (int d = 0; d < NCH; ++d) {
                const float x = sE[le][d];
                a0 += x * sW[o + 0][d];
                a1 += x * sW[o + 1][d];
                a2 += x * sW[o + 2][d];
                a3 += x * sW[o + 3][d];
            }
            float4 r;
            r.x = fmaxf(a0 + bias[o + 0], 0.f);
            r.y = fmaxf(a1 + bias[o + 1], 0.f);
            r.z = fmaxf(a2 + bias[o + 2], 0.f);
            r.w = fmaxf(a3 + bias[o + 3], 0.f);
            reinterpret_cast<float4*>(out)[(size_t)e * 32 + q] = r;
        }
        __syncthreads();
    }
}

// ---------------------------------------------------------------------------
extern "C" void kernel_launch(void* const* d_in, const int* in_sizes, int n_in,
                              void* d_out, int out_size, void* d_ws, size_t ws_size,
                              hipStream_t stream) {
    const float* X    = (const float*)d_in[0];   // [100000,128] f32
    const int*   ei   = (const int*)d_in[1];     // [2,625000] int32
    const float* aw   = (const float*)d_in[2];   // [128] f32
    const float* W    = (const float*)d_in[3];   // [128,128] f32
    const float* bias = (const float*)d_in[4];   // [128] f32
    float* out = (float*)d_out;

    const int M = in_sizes[0] / NCH;             // 100000 nodes
    const int E = in_sizes[1] / 2;               // 625000 edges

    const size_t y_off   = 65536;                              // Wpb (32KB) + pad
    const size_t y_bytes = (size_t)M * NCH * sizeof(unsigned short); // 25.6 MB

    if (ws_size >= y_off + y_bytes) {
        short* Wpb = (short*)d_ws;
        unsigned short* Yh = (unsigned short*)((char*)d_ws + y_off);
        prep_kernel<<<1, 128, 0, stream>>>(aw, W, Wpb);
        node_gemm_mfma<<<(M + 63) / 64, 256, 0, stream>>>(X, Wpb, Yh, M);
        edge_out_half<<<(E + 15) / 16, 256, 0, stream>>>(Yh, ei, bias, out, E);
    } else {
        int grid = (E + 7) / 8;
        if (grid > 32768) grid = 32768;
        direct_edge_kernel<<<grid, 256, 0, stream>>>(X, ei, aw, W, bias, out, E);
    }
}

// Round 4
// 132.859 us; speedup vs baseline: 2.0112x; 1.1708x over previous
//
#include <hip/hip_runtime.h>
#include <hip/hip_fp16.h>
#include <cstdint>

#define NCH 128   // IN_CH == OUT_CH == 128
#define NSLICE 8  // 8 col-slices of 16 ch: 100000*16*2B = 3.2 MB/slice < 4 MB L2/XCD

typedef short short8v __attribute__((ext_vector_type(8)));
typedef unsigned short ushort4v __attribute__((ext_vector_type(4)));
typedef float f32x4  __attribute__((ext_vector_type(4)));

// f32 -> bf16 bits, round-to-nearest-even
static __device__ __forceinline__ short f2bf(float f) {
    unsigned u = __float_as_uint(f);
    u += 0x7FFFu + ((u >> 16) & 1u);
    return (short)(u >> 16);
}
static __device__ __forceinline__ unsigned short f2h(float f) {
    return __half_as_ushort(__float2half(f));
}
static __device__ __forceinline__ float h2f(unsigned short u) {
    return __half2float(__ushort_as_half(u));
}

// ---------------------------------------------------------------------------
// prep: a = softmax(attn_weights); Wpb[o][d] = bf16(W[o][d] * a[d])
// ---------------------------------------------------------------------------
__global__ __launch_bounds__(128)
void prep_kernel(const float* __restrict__ aw,
                 const float* __restrict__ W,
                 short* __restrict__ Wpb) {
    __shared__ float sa[NCH];
    const int t = threadIdx.x;
    sa[t] = aw[t];
    __syncthreads();
    float m = -1e30f;
#pragma unroll
    for (int d = 0; d < NCH; ++d) m = fmaxf(m, sa[d]);
    float s = 0.f;
#pragma unroll
    for (int d = 0; d < NCH; ++d) s += expf(sa[d] - m);
    const float av = expf(sa[t] - m) / s;
    __syncthreads();
    sa[t] = av;
    __syncthreads();
    for (int o = 0; o < NCH; ++o)
        Wpb[o * NCH + t] = f2bf(W[o * NCH + t] * sa[t]);
}

// ---------------------------------------------------------------------------
// node GEMM via MFMA 16x16x32 bf16, no LDS. Output in SLICED fp16 layout:
//   Ys[slice][node][c] = fp16( sum_d X[node][d] * Wp[slice*16+c][d] )
// block = 256 (4 waves); wave w covers rows w*16..+15, all 8 col-tiles.
// C/D: col = lane&15, row = (lane>>4)*4 + j   [m89-verified]
// ---------------------------------------------------------------------------
__global__ __launch_bounds__(256)
void node_gemm_mfma(const float* __restrict__ X,
                    const short* __restrict__ Wpb,
                    unsigned short* __restrict__ Ys, int M) {
    const int t    = threadIdx.x;
    const int wave = t >> 6;
    const int lane = t & 63;
    const int r    = lane & 15;
    const int kb   = lane >> 4;

    const int row  = blockIdx.x * 64 + wave * 16 + r;
    const int rowc = row < M ? row : M - 1;          // clamp; stores guarded
    const float* xr = X + (size_t)rowc * NCH;

    short8v a[4];
#pragma unroll
    for (int ks = 0; ks < 4; ++ks) {
        const float4 f0 = *reinterpret_cast<const float4*>(xr + ks * 32 + kb * 8);
        const float4 f1 = *reinterpret_cast<const float4*>(xr + ks * 32 + kb * 8 + 4);
        short8v v;
        v[0] = f2bf(f0.x); v[1] = f2bf(f0.y); v[2] = f2bf(f0.z); v[3] = f2bf(f0.w);
        v[4] = f2bf(f1.x); v[5] = f2bf(f1.y); v[6] = f2bf(f1.z); v[7] = f2bf(f1.w);
        a[ks] = v;
    }

    const int orow0 = blockIdx.x * 64 + wave * 16 + kb * 4;
#pragma unroll
    for (int tile = 0; tile < 8; ++tile) {
        f32x4 acc = {0.f, 0.f, 0.f, 0.f};
        const short* wr = Wpb + (size_t)(tile * 16 + r) * NCH;
#pragma unroll
        for (int ks = 0; ks < 4; ++ks) {
            const short8v b = *reinterpret_cast<const short8v*>(wr + ks * 32 + kb * 8);
            acc = __builtin_amdgcn_mfma_f32_16x16x32_bf16(a[ks], b, acc, 0, 0, 0);
        }
        unsigned short* sbase = Ys + (size_t)tile * M * 16;
#pragma unroll
        for (int j = 0; j < 4; ++j) {
            const int orow = orow0 + j;
            if (orow < M) sbase[(size_t)orow * 16 + r] = f2h(acc[j]);
        }
    }
}

// ---------------------------------------------------------------------------
// sliced edge kernel: out[e][slice*16+c] = relu(Ys[slice][src][c] +
//                                               Ys[slice][tgt][c] + b[..])
// slice = blockIdx.x & 7  -> rides the XCD round-robin so each XCD's L2
// only sees its own 3.2 MB slice. 64 edges/block, 4 lanes/edge (8B gathers,
// 16B out store). out via non-temporal stores (don't thrash L2).
// ---------------------------------------------------------------------------
__global__ __launch_bounds__(256)
void edge_out_sliced(const unsigned short* __restrict__ Ys,
                     const int* __restrict__ ei,
                     const float* __restrict__ bias,
                     float* __restrict__ out, int E, int M) {
    const unsigned bid = blockIdx.x;
    const int slice = bid & (NSLICE - 1);
    const int eblk  = bid >> 3;
    const int t  = threadIdx.x;
    const int e  = eblk * 64 + (t >> 2);
    const int cl = t & 3;
    if (e >= E) return;

    const int s = ei[e];
    const int g = ei[E + e];
    const unsigned short* base = Ys + (size_t)slice * M * 16 + cl * 4;

    const ushort4v hs = *reinterpret_cast<const ushort4v*>(base + (size_t)s * 16);
    const ushort4v ht = *reinterpret_cast<const ushort4v*>(base + (size_t)g * 16);
    const float4 vb = *reinterpret_cast<const float4*>(bias + slice * 16 + cl * 4);

    f32x4 r;
    r[0] = fmaxf(h2f(hs[0]) + h2f(ht[0]) + vb.x, 0.f);
    r[1] = fmaxf(h2f(hs[1]) + h2f(ht[1]) + vb.y, 0.f);
    r[2] = fmaxf(h2f(hs[2]) + h2f(ht[2]) + vb.z, 0.f);
    r[3] = fmaxf(h2f(hs[3]) + h2f(ht[3]) + vb.w, 0.f);

    f32x4* dst = reinterpret_cast<f32x4*>(out + (size_t)e * NCH + slice * 16 + cl * 4);
    __builtin_nontemporal_store(r, dst);
}

// ---------------------------------------------------------------------------
// fallback (only if ws too small): fully self-contained direct fp32 edge GEMM
// ---------------------------------------------------------------------------
__global__ __launch_bounds__(256)
void direct_edge_kernel(const float* __restrict__ X,
                        const int* __restrict__ ei,
                        const float* __restrict__ aw,
                        const float* __restrict__ W,
                        const float* __restrict__ bias,
                        float* __restrict__ out, int E) {
    __shared__ float sW[NCH][NCH + 1];
    __shared__ float sa[NCH];
    __shared__ float sE[8][NCH + 4];
    const int t = threadIdx.x;
    if (t < NCH) sa[t] = aw[t];
    __syncthreads();
    float m = -1e30f;
#pragma unroll
    for (int d = 0; d < NCH; ++d) m = fmaxf(m, sa[d]);
    float ssum = 0.f;
#pragma unroll
    for (int d = 0; d < NCH; ++d) ssum += expf(sa[d] - m);
    const float av = (t < NCH) ? expf(sa[t] - m) / ssum : 0.f;
    __syncthreads();
    if (t < NCH) sa[t] = av;
    __syncthreads();
    for (int i = t; i < NCH * 32; i += 256) {
        const int o = i >> 5, q = i & 31;
        float4 v = reinterpret_cast<const float4*>(W)[o * 32 + q];
        sW[o][q * 4 + 0] = v.x * sa[q * 4 + 0];
        sW[o][q * 4 + 1] = v.y * sa[q * 4 + 1];
        sW[o][q * 4 + 2] = v.z * sa[q * 4 + 2];
        sW[o][q * 4 + 3] = v.w * sa[q * 4 + 3];
    }
    __syncthreads();
    const int le = t >> 5, q = t & 31;
    for (int e0 = blockIdx.x * 8; e0 < E; e0 += gridDim.x * 8) {
        const int e = e0 + le;
        if (e < E) {
            const int s = ei[e];
            const int g = ei[E + e];
            const float4 vs = reinterpret_cast<const float4*>(X)[(size_t)s * 32 + q];
            const float4 vt = reinterpret_cast<const float4*>(X)[(size_t)g * 32 + q];
            sE[le][q * 4 + 0] = vs.x + vt.x;
            sE[le][q * 4 + 1] = vs.y + vt.y;
            sE[le][q * 4 + 2] = vs.z + vt.z;
            sE[le][q * 4 + 3] = vs.w + vt.w;
        }
        __syncthreads();
        if (e < E) {
            float a0 = 0.f, a1 = 0.f, a2 = 0.f, a3 = 0.f;
            const int o = q * 4;
#pragma unroll 4
            for (int d = 0; d < NCH; ++d) {
                const float x = sE[le][d];
                a0 += x * sW[o + 0][d];
                a1 += x * sW[o + 1][d];
                a2 += x * sW[o + 2][d];
                a3 += x * sW[o + 3][d];
            }
            float4 r;
            r.x = fmaxf(a0 + bias[o + 0], 0.f);
            r.y = fmaxf(a1 + bias[o + 1], 0.f);
            r.z = fmaxf(a2 + bias[o + 2], 0.f);
            r.w = fmaxf(a3 + bias[o + 3], 0.f);
            reinterpret_cast<float4*>(out)[(size_t)e * 32 + q] = r;
        }
        __syncthreads();
    }
}

// ---------------------------------------------------------------------------
extern "C" void kernel_launch(void* const* d_in, const int* in_sizes, int n_in,
                              void* d_out, int out_size, void* d_ws, size_t ws_size,
                              hipStream_t stream) {
    const float* X    = (const float*)d_in[0];   // [100000,128] f32
    const int*   ei   = (const int*)d_in[1];     // [2,625000] int32
    const float* aw   = (const float*)d_in[2];   // [128] f32
    const float* W    = (const float*)d_in[3];   // [128,128] f32
    const float* bias = (const float*)d_in[4];   // [128] f32
    float* out = (float*)d_out;

    const int M = in_sizes[0] / NCH;             // 100000 nodes
    const int E = in_sizes[1] / 2;               // 625000 edges

    const size_t y_off   = 65536;                                    // Wpb (32KB) + pad
    const size_t y_bytes = (size_t)M * NCH * sizeof(unsigned short); // 25.6 MB sliced

    if (ws_size >= y_off + y_bytes) {
        short* Wpb = (short*)d_ws;
        unsigned short* Ys = (unsigned short*)((char*)d_ws + y_off);
        prep_kernel<<<1, 128, 0, stream>>>(aw, W, Wpb);
        node_gemm_mfma<<<(M + 63) / 64, 256, 0, stream>>>(X, Wpb, Ys, M);
        const int eblks = (E + 63) / 64;
        edge_out_sliced<<<eblks * NSLICE, 256, 0, stream>>>(Ys, ei, bias, out, E, M);
    } else {
        int grid = (E + 7) / 8;
        if (grid > 32768) grid = 32768;
        direct_edge_kernel<<<grid, 256, 0, stream>>>(X, ei, aw, W, bias, out, E);
    }
}